// Round 5
// baseline (373.614 us; speedup 1.0000x reference)
//
#include <hip/hip_runtime.h>
#include <hip/hip_bf16.h>
#include <math.h>

typedef __attribute__((ext_vector_type(8))) short bf16x8;
typedef __attribute__((ext_vector_type(4))) float f32x4;

#define HH 512
#define WW 512
#define CC 32

__device__ __forceinline__ unsigned short f2bf(float f) {
    unsigned u = __float_as_uint(f);
    u = (u + 0x7fffu + ((u >> 16) & 1u)) >> 16;
    return (unsigned short)u;
}

// Kernel A: fused conv3x3(C32->C32, SAME, zero pad) + BN(eval) + SiLU + conv1x1(C32->1)
// Implicit GEMM: M = pixels (16 consecutive j per MFMA tile), N = co(32), K = 288 ordered (kk, ci)
// so MFMA K-step t == tap position t (di = t/3-1, dj = t%3-1), K-lane index == ci.
__global__ __launch_bounds__(256) void conv_fused(
    const float* __restrict__ cen, const float* __restrict__ wconv,
    const float* __restrict__ gamma, const float* __restrict__ beta,
    const float* __restrict__ mean, const float* __restrict__ var,
    const float* __restrict__ w1x1, const float* __restrict__ b1x1,
    float* __restrict__ xout)
{
    // channels-last input tile with halo: [y:18][x:34][ci:32] bf16 = 39168 B
    __shared__ unsigned short sIn[18 * 34 * 32];
    // weights in B-frag layout: [t:9][h:4][co:32][e:8] bf16 = 18432 B, element = w[co][ci=8h+e][t]
    __shared__ unsigned short sW[9 * 4 * 32 * 8];

    const int tid = threadIdx.x;
    const int b  = blockIdx.z;
    const int i0 = blockIdx.y << 4;   // 16 rows per block
    const int j0 = blockIdx.x << 5;   // 32 cols per block

    // ---- stage weights (9216 f32, coalesced read, scattered u16 LDS write) ----
    for (int e = tid; e < 9216; e += 256) {
        int co  = e / 288;
        int rem = e - co * 288;
        int ci  = rem / 9;
        int t   = rem - ci * 9;
        sW[((t * 4 + (ci >> 3)) * 32 + co) * 8 + (ci & 7)] = f2bf(wconv[e]);
    }
    // ---- stage input tile, channels-last, zero-padded, 2 channels packed per b32 write ----
    for (int e = tid; e < 16 * 612; e += 256) {
        int cp = e / 612;            // channel pair 0..15
        int sp = e - cp * 612;       // y*34 + x
        int y = sp / 34, x = sp - y * 34;
        int gy = i0 - 1 + y, gx = j0 - 1 + x;
        float v0 = 0.f, v1 = 0.f;
        if ((unsigned)gy < HH && (unsigned)gx < WW) {
            const float* p = cen + (((long)(b * CC + 2 * cp) * HH + gy) * WW + gx);
            v0 = p[0];
            v1 = p[(long)HH * WW];
        }
        unsigned pk = (unsigned)f2bf(v0) | ((unsigned)f2bf(v1) << 16);
        *(unsigned*)&sIn[sp * 32 + 2 * cp] = pk;
    }
    __syncthreads();

    const int lane = tid & 63;
    const int wv   = tid >> 6;      // wave 0..3
    const int l15  = lane & 15;
    const int h    = lane >> 4;     // 0..3

    // preload all B fragments: 9 taps x 2 co-tiles, 8 bf16 each
    bf16x8 Bf[9][2];
#pragma unroll
    for (int t = 0; t < 9; ++t)
#pragma unroll
        for (int n = 0; n < 2; ++n)
            Bf[t][n] = *(const bf16x8*)&sW[((t * 4 + h) * 32 + n * 16 + l15) * 8];

    // per-lane BN / 1x1 constants for co = l15 and co = l15+16
    const float iv0 = gamma[l15]      / sqrtf(var[l15]      + 1e-5f);
    const float iv1 = gamma[l15 + 16] / sqrtf(var[l15 + 16] + 1e-5f);
    const float bb0 = beta[l15]      - mean[l15]      * iv0;
    const float bb1 = beta[l15 + 16] - mean[l15 + 16] * iv1;
    const float wa0 = w1x1[l15], wa1 = w1x1[l15 + 16];
    const float bias = b1x1[0];

    // each wave: 4 i-rows x 2 j-groups of 16 = 8 M-tiles
#pragma unroll
    for (int mt = 0; mt < 8; ++mt) {
        const int iloc = wv * 4 + (mt >> 1);
        const int jg   = mt & 1;
        const int xb   = jg * 16 + l15;   // j_loc; sIn x = xb + t%3 (halo offset folded)
        f32x4 acc0 = {0.f, 0.f, 0.f, 0.f};
        f32x4 acc1 = {0.f, 0.f, 0.f, 0.f};
#pragma unroll
        for (int t = 0; t < 9; ++t) {
            const int y = iloc + t / 3;
            const int x = xb + t % 3;
            bf16x8 A = *(const bf16x8*)&sIn[(y * 34 + x) * 32 + 8 * h];
            acc0 = __builtin_amdgcn_mfma_f32_16x16x32_bf16(A, Bf[t][0], acc0, 0, 0, 0);
            acc1 = __builtin_amdgcn_mfma_f32_16x16x32_bf16(A, Bf[t][1], acc1, 0, 0, 0);
        }
        // epilogue: BN + SiLU + 1x1 reduction over co (16 lanes x 2 frags)
        float v[4];
#pragma unroll
        for (int r = 0; r < 4; ++r) {
            float y0 = acc0[r] * iv0 + bb0;
            float y1 = acc1[r] * iv1 + bb1;
            float s0 = y0 / (1.f + __expf(-y0));
            float s1 = y1 / (1.f + __expf(-y1));
            v[r] = wa0 * s0 + wa1 * s1;
        }
#pragma unroll
        for (int m = 1; m <= 8; m <<= 1) {
#pragma unroll
            for (int r = 0; r < 4; ++r)
                v[r] += __shfl_xor(v[r], m, 64);
        }
        if (l15 == 0) {
            const int i = i0 + iloc;
            const int j = j0 + jg * 16 + 4 * h;   // D row = 4h + r = pixel j offset
            f32x4 o = {v[0] + bias, v[1] + bias, v[2] + bias, v[3] + bias};
            *(f32x4*)&xout[((long)b * HH + i) * WW + j] = o;
        }
    }
}

__device__ __forceinline__ float ldx(const float* __restrict__ xp, int i, int j) {
    return ((unsigned)i < HH && (unsigned)j < WW) ? xp[i * WW + j] : 0.f;
}

// Kernel B: shifted-difference products -> att, then out = cen * att. 4 pixels / thread.
__global__ __launch_bounds__(256) void att_mul(
    const float* __restrict__ xin, const float* __restrict__ cen,
    float* __restrict__ out)
{
    const int t  = blockIdx.x * 256 + threadIdx.x;   // 0 .. 4*512*128
    const int j4 = t & 127;
    const int i  = (t >> 7) & 511;
    const int b  = t >> 16;
    const float* xp = xin + (long)b * HH * WW;
    const int j = j4 << 2;

    float att[4];
#pragma unroll
    for (int p = 0; p < 4; ++p) {
        const int jj = j + p;
        const float c = xp[i * WW + jj];
        float o[2];
#pragma unroll
        for (int si = 0; si < 2; ++si) {
            const int s = si ? 3 : 1;
            float um = ldx(xp, i - s, jj - s), uc = ldx(xp, i - s, jj), up = ldx(xp, i - s, jj + s);
            float lm = ldx(xp, i,     jj - s),                          rp = ldx(xp, i,     jj + s);
            float dm = ldx(xp, i + s, jj - s), dc = ldx(xp, i + s, jj), dp = ldx(xp, i + s, jj + s);
            float d0 = (c - um) * (c - dp);
            float d1 = (c - uc) * (c - dc);
            float d2 = (c - up) * (c - dm);
            float d3 = (c - lm) * (c - rp);
            o[si] = fminf(fminf(d0, d1), fminf(d2, d3));
        }
        float a = 0.5f * (fmaxf(o[0], o[1]) + 0.5f * (o[0] + o[1]));
        a = a > 0.f ? a : 0.f;
        att[p] = 1.f / (1.f + __expf(-a));
    }

    const long rowoff = ((long)b * CC * HH + i) * WW + j;
#pragma unroll 4
    for (int c = 0; c < CC; ++c) {
        const long off = rowoff + (long)c * HH * WW;
        f32x4 v = *(const f32x4*)&cen[off];
        v.x *= att[0]; v.y *= att[1]; v.z *= att[2]; v.w *= att[3];
        *(f32x4*)&out[off] = v;
    }
}

extern "C" void kernel_launch(void* const* d_in, const int* in_sizes, int n_in,
                              void* d_out, int out_size, void* d_ws, size_t ws_size,
                              hipStream_t stream) {
    const float* cen   = (const float*)d_in[0];
    const float* wconv = (const float*)d_in[1];
    const float* gamma = (const float*)d_in[2];
    const float* beta  = (const float*)d_in[3];
    const float* mean  = (const float*)d_in[4];
    const float* var   = (const float*)d_in[5];
    const float* w1x1  = (const float*)d_in[6];
    const float* b1x1  = (const float*)d_in[7];
    float* xbuf = (float*)d_ws;            // [4][512][512] f32 = 4 MB
    float* outp = (float*)d_out;

    conv_fused<<<dim3(16, 32, 4), 256, 0, stream>>>(
        cen, wconv, gamma, beta, mean, var, w1x1, b1x1, xbuf);
    att_mul<<<dim3(1024), 256, 0, stream>>>(xbuf, cen, outp);
}

// Round 8
// 357.472 us; speedup vs baseline: 1.0452x; 1.0452x over previous
//
#include <hip/hip_runtime.h>
#include <hip/hip_bf16.h>
#include <math.h>

typedef __attribute__((ext_vector_type(8))) short bf16x8;
typedef __attribute__((ext_vector_type(4))) float f32x4;

#define HH 512
#define WW 512
#define CC 32

__device__ __forceinline__ unsigned short f2bf(float f) {
    unsigned u = __float_as_uint(f);
    u = (u + 0x7fffu + ((u >> 16) & 1u)) >> 16;
    return (unsigned short)u;
}

// One-shot weight prepack: wconv [co:32][ci:32][3][3] f32 -> wbuf u16 [t:9][h:4][co:32][e:8]
// (B-fragment layout for mfma_16x16x32_bf16: element = w[co][ci=8h+e][t])
__global__ __launch_bounds__(256) void prepack(const float* __restrict__ wconv,
                                               unsigned short* __restrict__ wbuf) {
    int e = blockIdx.x * 256 + threadIdx.x;
    if (e < 9216) {
        int co  = e / 288;
        int rem = e - co * 288;
        int ci  = rem / 9;
        int t   = rem - ci * 9;
        wbuf[((t * 4 + (ci >> 3)) * 32 + co) * 8 + (ci & 7)] = f2bf(wconv[e]);
    }
}

// Kernel A: fused conv3x3(C32->C32, SAME) + BN(eval) + SiLU + conv1x1(C32->1)
// Implicit GEMM; weights pre-packed in global (L2-broadcast); sIn XOR-swizzled.
__global__ __launch_bounds__(256) void conv_fused(
    const float* __restrict__ cen, const unsigned short* __restrict__ wbuf,
    const float* __restrict__ gamma, const float* __restrict__ beta,
    const float* __restrict__ mean, const float* __restrict__ var,
    const float* __restrict__ w1x1, const float* __restrict__ b1x1,
    float* __restrict__ xout)
{
    // channels-last input tile with halo: [sp = y*34+x : 612][chunk:4][2B*8ch] bf16 = 39168 B
    // chunk is XOR-swizzled with (sp&3): chunk_stored = group ^ (sp&3)
    __shared__ unsigned short sIn[18 * 34 * 32];

    const int tid = threadIdx.x;
    const int b  = blockIdx.z;
    const int i0 = blockIdx.y << 4;   // 16 rows per block
    const int j0 = blockIdx.x << 5;   // 32 cols per block

    // ---- stage input tile: e -> (cp = e&15 channel-pair, sp interleaved in upper bits)
    // one wave = 16 channel-pairs x 4 consecutive pixels -> LDS banks 2-way (free),
    // global reads 16B-contiguous per channel plane.
    for (int e = tid; e < 16 * 612; e += 256) {
        int cp = e & 15;
        int sp = ((e >> 6) << 2) | ((e >> 4) & 3);
        int y = sp / 34, x = sp - y * 34;
        int gy = i0 - 1 + y, gx = j0 - 1 + x;
        float v0 = 0.f, v1 = 0.f;
        if ((unsigned)gy < HH && (unsigned)gx < WW) {
            const float* p = cen + (((long)(b * CC + 2 * cp) * HH + gy) * WW + gx);
            v0 = p[0];
            v1 = p[(long)HH * WW];
        }
        unsigned pk = (unsigned)f2bf(v0) | ((unsigned)f2bf(v1) << 16);
        int off = sp * 32 + ((((cp >> 2) ^ (sp & 3)) << 3) | ((cp & 3) << 1));
        *(unsigned*)&sIn[off] = pk;
    }

    const int lane = tid & 63;
    const int wv   = tid >> 6;      // wave 0..3
    const int l15  = lane & 15;
    const int h    = lane >> 4;     // 0..3

    // preload all B fragments from global (identical across blocks -> L2 hit)
    bf16x8 Bf[9][2];
#pragma unroll
    for (int t = 0; t < 9; ++t)
#pragma unroll
        for (int n = 0; n < 2; ++n)
            Bf[t][n] = *(const bf16x8*)&wbuf[((t * 4 + h) * 32 + n * 16 + l15) * 8];

    // per-lane BN / 1x1 constants for co = l15 and co = l15+16
    const float iv0 = gamma[l15]      / sqrtf(var[l15]      + 1e-5f);
    const float iv1 = gamma[l15 + 16] / sqrtf(var[l15 + 16] + 1e-5f);
    const float bb0 = beta[l15]      - mean[l15]      * iv0;
    const float bb1 = beta[l15 + 16] - mean[l15 + 16] * iv1;
    const float wa0 = w1x1[l15], wa1 = w1x1[l15 + 16];
    const float bias = b1x1[0];

    __syncthreads();

    // each wave: 4 i-rows x 2 j-groups of 16 = 8 M-tiles
#pragma unroll
    for (int mt = 0; mt < 8; ++mt) {
        const int iloc = wv * 4 + (mt >> 1);
        const int jg   = mt & 1;
        const int xb   = jg * 16 + l15;   // j_loc; sIn x = xb + t%3 (halo offset folded)
        f32x4 acc0 = {0.f, 0.f, 0.f, 0.f};
        f32x4 acc1 = {0.f, 0.f, 0.f, 0.f};
#pragma unroll
        for (int t = 0; t < 9; ++t) {
            const int sp = (iloc + t / 3) * 34 + xb + t % 3;
            bf16x8 A = *(const bf16x8*)&sIn[sp * 32 + ((h ^ (sp & 3)) << 3)];
            acc0 = __builtin_amdgcn_mfma_f32_16x16x32_bf16(A, Bf[t][0], acc0, 0, 0, 0);
            acc1 = __builtin_amdgcn_mfma_f32_16x16x32_bf16(A, Bf[t][1], acc1, 0, 0, 0);
        }
        // epilogue: BN + SiLU + 1x1 reduction over co (16 lanes x 2 frags)
        float v[4];
#pragma unroll
        for (int r = 0; r < 4; ++r) {
            float y0 = acc0[r] * iv0 + bb0;
            float y1 = acc1[r] * iv1 + bb1;
            float s0 = y0 / (1.f + __expf(-y0));
            float s1 = y1 / (1.f + __expf(-y1));
            v[r] = wa0 * s0 + wa1 * s1;
        }
#pragma unroll
        for (int m = 1; m <= 8; m <<= 1) {
#pragma unroll
            for (int r = 0; r < 4; ++r)
                v[r] += __shfl_xor(v[r], m, 64);
        }
        if (l15 == 0) {
            const int i = i0 + iloc;
            const int j = j0 + jg * 16 + 4 * h;   // D row = 4h + r = pixel j offset
            f32x4 o = {v[0] + bias, v[1] + bias, v[2] + bias, v[3] + bias};
            *(f32x4*)&xout[((long)b * HH + i) * WW + j] = o;
        }
    }
}

__device__ __forceinline__ float ldx(const float* __restrict__ xp, int i, int j) {
    return ((unsigned)i < HH && (unsigned)j < WW) ? xp[i * WW + j] : 0.f;
}

// Kernel B: shifted-difference products -> att, then out = cen * att. 4 pixels / thread.
__global__ __launch_bounds__(256) void att_mul(
    const float* __restrict__ xin, const float* __restrict__ cen,
    float* __restrict__ out)
{
    const int t  = blockIdx.x * 256 + threadIdx.x;   // 0 .. 4*512*128
    const int j4 = t & 127;
    const int i  = (t >> 7) & 511;
    const int b  = t >> 16;
    const float* xp = xin + (long)b * HH * WW;
    const int j = j4 << 2;

    float att[4];
#pragma unroll
    for (int p = 0; p < 4; ++p) {
        const int jj = j + p;
        const float c = xp[i * WW + jj];
        float o[2];
#pragma unroll
        for (int si = 0; si < 2; ++si) {
            const int s = si ? 3 : 1;
            float um = ldx(xp, i - s, jj - s), uc = ldx(xp, i - s, jj), up = ldx(xp, i - s, jj + s);
            float lm = ldx(xp, i,     jj - s),                          rp = ldx(xp, i,     jj + s);
            float dm = ldx(xp, i + s, jj - s), dc = ldx(xp, i + s, jj), dp = ldx(xp, i + s, jj + s);
            float d0 = (c - um) * (c - dp);
            float d1 = (c - uc) * (c - dc);
            float d2 = (c - up) * (c - dm);
            float d3 = (c - lm) * (c - rp);
            o[si] = fminf(fminf(d0, d1), fminf(d2, d3));
        }
        float a = 0.5f * (fmaxf(o[0], o[1]) + 0.5f * (o[0] + o[1]));
        a = a > 0.f ? a : 0.f;
        att[p] = 1.f / (1.f + __expf(-a));
    }

    const long rowoff = ((long)b * CC * HH + i) * WW + j;
#pragma unroll 8
    for (int c = 0; c < CC; ++c) {
        const long off = rowoff + (long)c * HH * WW;
        f32x4 v = *(const f32x4*)&cen[off];
        v.x *= att[0]; v.y *= att[1]; v.z *= att[2]; v.w *= att[3];
        *(f32x4*)&out[off] = v;
    }
}

extern "C" void kernel_launch(void* const* d_in, const int* in_sizes, int n_in,
                              void* d_out, int out_size, void* d_ws, size_t ws_size,
                              hipStream_t stream) {
    const float* cen   = (const float*)d_in[0];
    const float* wconv = (const float*)d_in[1];
    const float* gamma = (const float*)d_in[2];
    const float* beta  = (const float*)d_in[3];
    const float* mean  = (const float*)d_in[4];
    const float* var   = (const float*)d_in[5];
    const float* w1x1  = (const float*)d_in[6];
    const float* b1x1  = (const float*)d_in[7];
    float* xbuf = (float*)d_ws;                                   // [4][512][512] f32 = 4 MB
    unsigned short* wbuf = (unsigned short*)((char*)d_ws + (4l << 20)); // 9216 u16 = 18 KB
    float* outp = (float*)d_out;

    prepack<<<dim3(36), 256, 0, stream>>>(wconv, wbuf);
    conv_fused<<<dim3(16, 32, 4), 256, 0, stream>>>(
        cen, wbuf, gamma, beta, mean, var, w1x1, b1x1, xbuf);
    att_mul<<<dim3(1024), 256, 0, stream>>>(xbuf, cen, outp);
}

// Round 9
// 316.379 us; speedup vs baseline: 1.1809x; 1.1299x over previous
//
#include <hip/hip_runtime.h>
#include <hip/hip_bf16.h>
#include <math.h>

typedef __attribute__((ext_vector_type(8))) short bf16x8;
typedef __attribute__((ext_vector_type(4))) float f32x4;

#define HH 512
#define WW 512
#define CC 32

__device__ __forceinline__ unsigned short f2bf(float f) {
    unsigned u = __float_as_uint(f);
    u = (u + 0x7fffu + ((u >> 16) & 1u)) >> 16;
    return (unsigned short)u;
}

// One-shot weight prepack: wconv [co:32][ci:32][3][3] f32 -> wbuf u16 [t:9][h:4][co:32][e:8]
// (B-fragment layout for mfma_16x16x32_bf16: element = w[co][ci=8h+e][t])
__global__ __launch_bounds__(256) void prepack(const float* __restrict__ wconv,
                                               unsigned short* __restrict__ wbuf) {
    int e = blockIdx.x * 256 + threadIdx.x;
    if (e < 9216) {
        int co  = e / 288;
        int rem = e - co * 288;
        int ci  = rem / 9;
        int t   = rem - ci * 9;
        wbuf[((t * 4 + (ci >> 3)) * 32 + co) * 8 + (ci & 7)] = f2bf(wconv[e]);
    }
}

// Kernel A: fused conv3x3(C32->C32, SAME) + BN(eval) + SiLU + conv1x1(C32->1)
// Implicit GEMM. Staging uses WIDE f32x4 loads (4 px x 2 channels per iter) into a
// 40-px-wide channels-last LDS tile (16B-aligned quads, edge quads all-or-nothing).
__global__ __launch_bounds__(256) void conv_fused(
    const float* __restrict__ cen, const unsigned short* __restrict__ wbuf,
    const float* __restrict__ gamma, const float* __restrict__ beta,
    const float* __restrict__ mean, const float* __restrict__ var,
    const float* __restrict__ w1x1, const float* __restrict__ b1x1,
    float* __restrict__ xout)
{
    // [sp = y*40 + px : 720][chunk:4][2B*8ch] bf16 = 46080 B; chunk XOR-swizzled by sp&3
    __shared__ unsigned short sIn[18 * 40 * 32];

    const int tid = threadIdx.x;
    const int b  = blockIdx.z;
    const int i0 = blockIdx.y << 4;   // 16 rows per block
    const int j0 = blockIdx.x << 5;   // 32 cols per block

    // ---- stage: 18 rows x 10 px-quads x 16 channel-pairs = 2880 tasks ----
    for (int e = tid; e < 2880; e += 256) {
        int r   = e / 160;            // row 0..17
        int rem = e - r * 160;
        int cp  = rem & 15;           // channel pair
        int q   = rem >> 4;           // px quad 0..9
        int gy  = i0 - 1 + r;
        int gx0 = j0 - 4 + 4 * q;     // 16B aligned; quad fully in or fully out
        f32x4 v0 = {0.f, 0.f, 0.f, 0.f}, v1 = {0.f, 0.f, 0.f, 0.f};
        if ((unsigned)gy < HH && (unsigned)gx0 < (WW - 3)) {
            const float* p = cen + (((long)(b * CC + 2 * cp) * HH + gy) * WW + gx0);
            v0 = *(const f32x4*)p;
            v1 = *(const f32x4*)(p + (long)HH * WW);
        }
        const int spb = r * 40 + 4 * q;
#pragma unroll
        for (int p2 = 0; p2 < 4; ++p2) {
            int sp = spb + p2;
            unsigned pk = (unsigned)f2bf(v0[p2]) | ((unsigned)f2bf(v1[p2]) << 16);
            int off = sp * 32 + ((((cp >> 2) ^ (sp & 3)) << 3) | ((cp & 3) << 1));
            *(unsigned*)&sIn[off] = pk;
        }
    }

    const int lane = tid & 63;
    const int wv   = tid >> 6;      // wave 0..3
    const int l15  = lane & 15;
    const int h    = lane >> 4;     // 0..3

    // preload all B fragments from global (identical across blocks -> L2 hit)
    bf16x8 Bf[9][2];
#pragma unroll
    for (int t = 0; t < 9; ++t)
#pragma unroll
        for (int n = 0; n < 2; ++n)
            Bf[t][n] = *(const bf16x8*)&wbuf[((t * 4 + h) * 32 + n * 16 + l15) * 8];

    // per-lane BN / 1x1 constants for co = l15 and co = l15+16
    const float iv0 = gamma[l15]      / sqrtf(var[l15]      + 1e-5f);
    const float iv1 = gamma[l15 + 16] / sqrtf(var[l15 + 16] + 1e-5f);
    const float bb0 = beta[l15]      - mean[l15]      * iv0;
    const float bb1 = beta[l15 + 16] - mean[l15 + 16] * iv1;
    const float wa0 = w1x1[l15], wa1 = w1x1[l15 + 16];
    const float bias = b1x1[0];

    __syncthreads();

    // each wave: 4 i-rows x 2 j-groups of 16 = 8 M-tiles
#pragma unroll
    for (int mt = 0; mt < 8; ++mt) {
        const int iloc = wv * 4 + (mt >> 1);
        const int jg   = mt & 1;
        const int xb   = jg * 16 + l15;   // local j; LDS px = xb + t%3 + 3 (halo fold)
        f32x4 acc0 = {0.f, 0.f, 0.f, 0.f};
        f32x4 acc1 = {0.f, 0.f, 0.f, 0.f};
#pragma unroll
        for (int t = 0; t < 9; ++t) {
            const int sp = (iloc + t / 3) * 40 + xb + t % 3 + 3;
            bf16x8 A = *(const bf16x8*)&sIn[sp * 32 + ((h ^ (sp & 3)) << 3)];
            acc0 = __builtin_amdgcn_mfma_f32_16x16x32_bf16(A, Bf[t][0], acc0, 0, 0, 0);
            acc1 = __builtin_amdgcn_mfma_f32_16x16x32_bf16(A, Bf[t][1], acc1, 0, 0, 0);
        }
        // epilogue: BN + SiLU + 1x1 reduction over co (16 lanes x 2 frags)
        float v[4];
#pragma unroll
        for (int r = 0; r < 4; ++r) {
            float y0 = acc0[r] * iv0 + bb0;
            float y1 = acc1[r] * iv1 + bb1;
            float s0 = y0 / (1.f + __expf(-y0));
            float s1 = y1 / (1.f + __expf(-y1));
            v[r] = wa0 * s0 + wa1 * s1;
        }
#pragma unroll
        for (int m = 1; m <= 8; m <<= 1) {
#pragma unroll
            for (int r = 0; r < 4; ++r)
                v[r] += __shfl_xor(v[r], m, 64);
        }
        if (l15 == 0) {
            const int i = i0 + iloc;
            const int j = j0 + jg * 16 + 4 * h;   // D row = 4h + r = pixel j offset
            f32x4 o = {v[0] + bias, v[1] + bias, v[2] + bias, v[3] + bias};
            *(f32x4*)&xout[((long)b * HH + i) * WW + j] = o;
        }
    }
}

// Kernel B: shifted-difference products -> att, out = cen * att.
// Block = 2 rows x 512 px. x staged in LDS (8 rows x 520 px, zero-padded);
// stencil reads are aligned ds_read_b128 into a register window (all static idx).
__global__ __launch_bounds__(256) void att_mul(
    const float* __restrict__ xin, const float* __restrict__ cen,
    float* __restrict__ out)
{
    __shared__ float xs[8 * 520];     // 16640 B
    const int tid = threadIdx.x;
    const int b   = blockIdx.x >> 8;
    const int ip  = blockIdx.x & 255;     // row pair index
    const int gy0 = 2 * ip - 3;
    const float* xp = xin + (long)b * HH * WW;

    // stage 8 rows x 130 quads (px -4..515, OOB quads -> 0)
    for (int e = tid; e < 1040; e += 256) {
        int r  = e / 130;
        int q  = e - r * 130;
        int gy = gy0 + r;
        int gx0 = 4 * q - 4;
        f32x4 v = {0.f, 0.f, 0.f, 0.f};
        if ((unsigned)gy < HH && (unsigned)gx0 < (WW - 3))
            v = *(const f32x4*)&xp[gy * WW + gx0];
        *(f32x4*)&xs[r * 520 + 4 * q] = v;
    }
    __syncthreads();

    const int jq = tid & 127;         // col quad
    const int il = tid >> 7;          // row-in-pair 0/1
    const int i  = 2 * ip + il;
    const int j  = jq << 2;

    // register windows: rows i-3, i-1, i, i+1, i+3; cols j-4 .. j+7 (value(d)=w[d+4])
    float w3m[12], w1m[12], wc0[12], w1p[12], w3p[12];
#pragma unroll
    for (int k = 0; k < 3; ++k) {
        f32x4 a;
        a = *(const f32x4*)&xs[(il + 0) * 520 + 4 * (jq + k)];
        w3m[4*k] = a.x; w3m[4*k+1] = a.y; w3m[4*k+2] = a.z; w3m[4*k+3] = a.w;
        a = *(const f32x4*)&xs[(il + 2) * 520 + 4 * (jq + k)];
        w1m[4*k] = a.x; w1m[4*k+1] = a.y; w1m[4*k+2] = a.z; w1m[4*k+3] = a.w;
        a = *(const f32x4*)&xs[(il + 3) * 520 + 4 * (jq + k)];
        wc0[4*k] = a.x; wc0[4*k+1] = a.y; wc0[4*k+2] = a.z; wc0[4*k+3] = a.w;
        a = *(const f32x4*)&xs[(il + 4) * 520 + 4 * (jq + k)];
        w1p[4*k] = a.x; w1p[4*k+1] = a.y; w1p[4*k+2] = a.z; w1p[4*k+3] = a.w;
        a = *(const f32x4*)&xs[(il + 6) * 520 + 4 * (jq + k)];
        w3p[4*k] = a.x; w3p[4*k+1] = a.y; w3p[4*k+2] = a.z; w3p[4*k+3] = a.w;
    }

    float att[4];
#pragma unroll
    for (int p = 0; p < 4; ++p) {
        const float c = wc0[p + 4];
        float d0 = (c - w1m[p + 3]) * (c - w1p[p + 5]);
        float d1 = (c - w1m[p + 4]) * (c - w1p[p + 4]);
        float d2 = (c - w1m[p + 5]) * (c - w1p[p + 3]);
        float d3 = (c - wc0[p + 3]) * (c - wc0[p + 5]);
        float o0 = fminf(fminf(d0, d1), fminf(d2, d3));
        d0 = (c - w3m[p + 1]) * (c - w3p[p + 7]);
        d1 = (c - w3m[p + 4]) * (c - w3p[p + 4]);
        d2 = (c - w3m[p + 7]) * (c - w3p[p + 1]);
        d3 = (c - wc0[p + 1]) * (c - wc0[p + 7]);
        float o1 = fminf(fminf(d0, d1), fminf(d2, d3));
        float a = 0.5f * (fmaxf(o0, o1) + 0.5f * (o0 + o1));
        a = a > 0.f ? a : 0.f;
        att[p] = 1.f / (1.f + __expf(-a));
    }

    const long rowoff = ((long)b * CC * HH + i) * WW + j;
#pragma unroll 8
    for (int c = 0; c < CC; ++c) {
        const long off = rowoff + (long)c * HH * WW;
        f32x4 v = *(const f32x4*)&cen[off];
        v.x *= att[0]; v.y *= att[1]; v.z *= att[2]; v.w *= att[3];
        *(f32x4*)&out[off] = v;
    }
}

extern "C" void kernel_launch(void* const* d_in, const int* in_sizes, int n_in,
                              void* d_out, int out_size, void* d_ws, size_t ws_size,
                              hipStream_t stream) {
    const float* cen   = (const float*)d_in[0];
    const float* wconv = (const float*)d_in[1];
    const float* gamma = (const float*)d_in[2];
    const float* beta  = (const float*)d_in[3];
    const float* mean  = (const float*)d_in[4];
    const float* var   = (const float*)d_in[5];
    const float* w1x1  = (const float*)d_in[6];
    const float* b1x1  = (const float*)d_in[7];
    float* xbuf = (float*)d_ws;                                        // 4 MB
    unsigned short* wbuf = (unsigned short*)((char*)d_ws + (4l << 20)); // 18 KB
    float* outp = (float*)d_out;

    prepack<<<dim3(36), 256, 0, stream>>>(wconv, wbuf);
    conv_fused<<<dim3(16, 32, 4), 256, 0, stream>>>(
        cen, wbuf, gamma, beta, mean, var, w1x1, b1x1, xbuf);
    att_mul<<<dim3(1024), 256, 0, stream>>>(xbuf, cen, outp);
}